// Round 1
// baseline (1576.152 us; speedup 1.0000x reference)
//
#include <hip/hip_runtime.h>

// Problem constants: B=4, H=W=128, D=64, NH=2, hd=32, 9 taps, pad=1.
// Input order: x, K_P[64,576], V_P[64,576], Q_P[64,64], ff1_k[64,64], ff1_b[64],
//              ff2_k[3,3,64,128], ff2_b[128], ff3_k[3,3,128,64], ff3_b[64]
// All fp32. Output: [4,128,128,64] fp32.

__device__ __forceinline__ float comp4(const float4& v, int i) {
  switch (i) { case 0: return v.x; case 1: return v.y; case 2: return v.z; default: return v.w; }
}

// ---------------- attention: fused projections + softmax + combine --------
// thread = (pixel, head). gid<65536 -> head0, else head1. Lanes within a wave
// share `head` and walk consecutive pixels -> weight loads are wave-broadcast.
__global__ __launch_bounds__(256) void attn_kernel(
    const float* __restrict__ x, const float* __restrict__ Kp,
    const float* __restrict__ Vp, const float* __restrict__ Qp,
    float* __restrict__ attnb)
{
  const int gid  = blockIdx.x * 256 + threadIdx.x;   // 131072 threads
  const int head = gid >> 16;                        // 0..1
  const int pix  = gid & 65535;
  const int h = (pix >> 7) & 127;
  const int w = pix & 127;
  const int hc = head * 32;

  // q = x_row @ Q_P[:, hc:hc+32]
  float q[32];
#pragma unroll
  for (int c = 0; c < 32; ++c) q[c] = 0.f;
  {
    const float4* xr4 = (const float4*)(x + pix * 64);
    for (int d4 = 0; d4 < 16; ++d4) {
      float4 xv = xr4[d4];
#pragma unroll
      for (int dd = 0; dd < 4; ++dd) {
        const float xd = comp4(xv, dd);
        const float4* wr = (const float4*)(Qp + (d4 * 4 + dd) * 64 + hc);
#pragma unroll
        for (int c4 = 0; c4 < 8; ++c4) {
          float4 wv = wr[c4];
          q[c4*4+0] += xd * wv.x; q[c4*4+1] += xd * wv.y;
          q[c4*4+2] += xd * wv.z; q[c4*4+3] += xd * wv.w;
        }
      }
    }
  }

  // scores: tap t uses chunk t of K projection of neighbor (h+dh, w+dw).
  // OOB taps: score = 0 (mask-then-/3 semantics of the reference).
  float sc[9];
#pragma unroll
  for (int t = 0; t < 9; ++t) {
    const int dh = t / 3 - 1, dw = t % 3 - 1;
    const int hn = h + dh, wn = w + dw;
    if ((unsigned)hn >= 128u || (unsigned)wn >= 128u) { sc[t] = 0.f; continue; }
    const float4* xn4 = (const float4*)(x + (pix + dh * 128 + dw) * 64);
    float s = 0.f;
    for (int d4 = 0; d4 < 16; ++d4) {
      float4 xv = xn4[d4];
#pragma unroll
      for (int dd = 0; dd < 4; ++dd) {
        const float xd = comp4(xv, dd);
        const float4* wr = (const float4*)(Kp + (d4 * 4 + dd) * 576 + t * 64 + hc);
        float part = 0.f;
#pragma unroll
        for (int c4 = 0; c4 < 8; ++c4) {
          float4 wv = wr[c4];
          part += q[c4*4+0] * wv.x + q[c4*4+1] * wv.y
                + q[c4*4+2] * wv.z + q[c4*4+3] * wv.w;
        }
        s += xd * part;
      }
    }
    sc[t] = s * (1.f / 3.f);
  }

  // softmax over 9 taps (OOB taps participate with score 0)
  float mx = sc[0];
#pragma unroll
  for (int t = 1; t < 9; ++t) mx = fmaxf(mx, sc[t]);
  float al[9]; float den = 0.f;
#pragma unroll
  for (int t = 0; t < 9; ++t) { al[t] = __expf(sc[t] - mx); den += al[t]; }
  const float inv = 1.f / den;

  // attn = sum_t alpha_t * (x[nb] @ V_chunk_t); OOB taps contribute zero value
  float at[32];
#pragma unroll
  for (int c = 0; c < 32; ++c) at[c] = 0.f;
#pragma unroll
  for (int t = 0; t < 9; ++t) {
    const int dh = t / 3 - 1, dw = t % 3 - 1;
    const int hn = h + dh, wn = w + dw;
    if ((unsigned)hn >= 128u || (unsigned)wn >= 128u) continue;
    const float a = al[t] * inv;
    const float4* xn4 = (const float4*)(x + (pix + dh * 128 + dw) * 64);
    for (int d4 = 0; d4 < 16; ++d4) {
      float4 xv = xn4[d4];
#pragma unroll
      for (int dd = 0; dd < 4; ++dd) {
        const float axd = a * comp4(xv, dd);
        const float4* wr = (const float4*)(Vp + (d4 * 4 + dd) * 576 + t * 64 + hc);
#pragma unroll
        for (int c4 = 0; c4 < 8; ++c4) {
          float4 wv = wr[c4];
          at[c4*4+0] += axd * wv.x; at[c4*4+1] += axd * wv.y;
          at[c4*4+2] += axd * wv.z; at[c4*4+3] += axd * wv.w;
        }
      }
    }
  }

  float4* o4 = (float4*)(attnb + pix * 64 + hc);
#pragma unroll
  for (int c4 = 0; c4 < 8; ++c4)
    o4[c4] = make_float4(at[c4*4+0], at[c4*4+1], at[c4*4+2], at[c4*4+3]);
}

// ---------------- ff1: 1x1 conv + bias + relu ----------------------------
// thread = (2 pixels, 16-channel group). g = gid>>15 in 0..3.
__global__ __launch_bounds__(256) void ff1_kernel(
    const float* __restrict__ in, const float* __restrict__ wgt,
    const float* __restrict__ bias, float* __restrict__ out)
{
  const int gid = blockIdx.x * 256 + threadIdx.x;    // 131072 threads
  const int g  = gid >> 15;                          // 0..3
  const int p2 = gid & 32767;
  const int pix0 = p2 * 2;

  float acc0[16], acc1[16];
#pragma unroll
  for (int c = 0; c < 16; ++c) { acc0[c] = 0.f; acc1[c] = 0.f; }

  const float4* x0 = (const float4*)(in + pix0 * 64);
  const float4* x1 = (const float4*)(in + pix0 * 64 + 64);
  for (int d4 = 0; d4 < 16; ++d4) {
    float4 a = x0[d4], b = x1[d4];
#pragma unroll
    for (int dd = 0; dd < 4; ++dd) {
      const float xa = comp4(a, dd), xb = comp4(b, dd);
      const float4* wr = (const float4*)(wgt + (d4 * 4 + dd) * 64 + g * 16);
#pragma unroll
      for (int c4 = 0; c4 < 4; ++c4) {
        float4 wv = wr[c4];
        acc0[c4*4+0] += xa * wv.x; acc0[c4*4+1] += xa * wv.y;
        acc0[c4*4+2] += xa * wv.z; acc0[c4*4+3] += xa * wv.w;
        acc1[c4*4+0] += xb * wv.x; acc1[c4*4+1] += xb * wv.y;
        acc1[c4*4+2] += xb * wv.z; acc1[c4*4+3] += xb * wv.w;
      }
    }
  }

  float4* o0 = (float4*)(out + pix0 * 64 + g * 16);
  float4* o1 = (float4*)(out + pix0 * 64 + 64 + g * 16);
#pragma unroll
  for (int c4 = 0; c4 < 4; ++c4) {
    float4 bv = ((const float4*)(bias + g * 16))[c4];
    o0[c4] = make_float4(fmaxf(acc0[c4*4+0] + bv.x, 0.f), fmaxf(acc0[c4*4+1] + bv.y, 0.f),
                         fmaxf(acc0[c4*4+2] + bv.z, 0.f), fmaxf(acc0[c4*4+3] + bv.w, 0.f));
    o1[c4] = make_float4(fmaxf(acc1[c4*4+0] + bv.x, 0.f), fmaxf(acc1[c4*4+1] + bv.y, 0.f),
                         fmaxf(acc1[c4*4+2] + bv.z, 0.f), fmaxf(acc1[c4*4+3] + bv.w, 0.f));
  }
}

// ---------------- 3x3 conv + bias + relu, SAME zero padding ---------------
// thread = (2 pixels, 16-of-COUT channel group). Weight layout HWIO.
template <int CIN, int COUT>
__global__ __launch_bounds__(256) void conv3_kernel(
    const float* __restrict__ in, const float* __restrict__ wgt,
    const float* __restrict__ bias, float* __restrict__ out)
{
  const int gid = blockIdx.x * 256 + threadIdx.x;
  const int g  = gid >> 15;            // COUT/16 groups
  const int p2 = gid & 32767;
  const int pix0 = p2 * 2, pix1 = pix0 + 1;
  const int h0 = (pix0 >> 7) & 127, w0 = pix0 & 127;
  const int h1 = (pix1 >> 7) & 127, w1 = pix1 & 127;

  float acc0[16], acc1[16];
#pragma unroll
  for (int c = 0; c < 16; ++c) { acc0[c] = 0.f; acc1[c] = 0.f; }

#pragma unroll
  for (int t = 0; t < 9; ++t) {
    const int dh = t / 3 - 1, dw = t % 3 - 1;
    const bool v0 = ((unsigned)(h0 + dh) < 128u) && ((unsigned)(w0 + dw) < 128u);
    const bool v1 = ((unsigned)(h1 + dh) < 128u) && ((unsigned)(w1 + dw) < 128u);
    const float4* xr0 = (const float4*)(in + (pix0 + dh * 128 + dw) * CIN);
    const float4* xr1 = (const float4*)(in + (pix1 + dh * 128 + dw) * CIN);
    for (int d4 = 0; d4 < CIN / 4; ++d4) {
      float4 a = make_float4(0.f, 0.f, 0.f, 0.f);
      float4 b = make_float4(0.f, 0.f, 0.f, 0.f);
      if (v0) a = xr0[d4];
      if (v1) b = xr1[d4];
#pragma unroll
      for (int dd = 0; dd < 4; ++dd) {
        const float xa = comp4(a, dd), xb = comp4(b, dd);
        const float4* wr = (const float4*)(wgt + (t * CIN + d4 * 4 + dd) * COUT + g * 16);
#pragma unroll
        for (int c4 = 0; c4 < 4; ++c4) {
          float4 wv = wr[c4];
          acc0[c4*4+0] += xa * wv.x; acc0[c4*4+1] += xa * wv.y;
          acc0[c4*4+2] += xa * wv.z; acc0[c4*4+3] += xa * wv.w;
          acc1[c4*4+0] += xb * wv.x; acc1[c4*4+1] += xb * wv.y;
          acc1[c4*4+2] += xb * wv.z; acc1[c4*4+3] += xb * wv.w;
        }
      }
    }
  }

  float4* o0 = (float4*)(out + pix0 * COUT + g * 16);
  float4* o1 = (float4*)(out + pix1 * COUT + g * 16);
#pragma unroll
  for (int c4 = 0; c4 < 4; ++c4) {
    float4 bv = ((const float4*)(bias + g * 16))[c4];
    o0[c4] = make_float4(fmaxf(acc0[c4*4+0] + bv.x, 0.f), fmaxf(acc0[c4*4+1] + bv.y, 0.f),
                         fmaxf(acc0[c4*4+2] + bv.z, 0.f), fmaxf(acc0[c4*4+3] + bv.w, 0.f));
    o1[c4] = make_float4(fmaxf(acc1[c4*4+0] + bv.x, 0.f), fmaxf(acc1[c4*4+1] + bv.y, 0.f),
                         fmaxf(acc1[c4*4+2] + bv.z, 0.f), fmaxf(acc1[c4*4+3] + bv.w, 0.f));
  }
}

extern "C" void kernel_launch(void* const* d_in, const int* in_sizes, int n_in,
                              void* d_out, int out_size, void* d_ws, size_t ws_size,
                              hipStream_t stream) {
  (void)in_sizes; (void)n_in; (void)out_size; (void)ws_size;
  const float* x   = (const float*)d_in[0];
  const float* Kp  = (const float*)d_in[1];
  const float* Vp  = (const float*)d_in[2];
  const float* Qp  = (const float*)d_in[3];
  const float* f1w = (const float*)d_in[4];
  const float* f1b = (const float*)d_in[5];
  const float* f2w = (const float*)d_in[6];
  const float* f2b = (const float*)d_in[7];
  const float* f3w = (const float*)d_in[8];
  const float* f3b = (const float*)d_in[9];
  float* out = (float*)d_out;

  // ws layout: attn buffer [65536*64] fp32 (16.78 MB) lives at ws start;
  // after ff1 consumes it, the same region is reused for t2 [65536*128] fp32
  // (33.55 MB). t1 uses d_out as scratch (fully overwritten by conv3).
  float* attnb = (float*)d_ws;
  float* t2    = (float*)d_ws;

  attn_kernel<<<512, 256, 0, stream>>>(x, Kp, Vp, Qp, attnb);          // attn -> ws
  ff1_kernel<<<512, 256, 0, stream>>>(attnb, f1w, f1b, out);           // t1 -> d_out
  conv3_kernel<64, 128><<<1024, 256, 0, stream>>>(out, f2w, f2b, t2);  // t2 -> ws
  conv3_kernel<128, 64><<<512, 256, 0, stream>>>(t2, f3w, f3b, out);   // out -> d_out
}

// Round 2
// 201.951 us; speedup vs baseline: 7.8046x; 7.8046x over previous
//
#include <hip/hip_runtime.h>

// B=4, H=W=128, D=64, NH=2, hd=32, 9 taps. All inputs fp32; compute in fp16 MFMA.
// Input order: x, K_P[64,576], V_P[64,576], Q_P[64,64], ff1_k[64,64], ff1_b[64],
//              ff2_k[3,3,64,128], ff2_b[128], ff3_k[3,3,128,64], ff3_b[64]

typedef _Float16 half8 __attribute__((ext_vector_type(8)));
typedef _Float16 half4v __attribute__((ext_vector_type(4)));
typedef float f32x4 __attribute__((ext_vector_type(4)));

__device__ __forceinline__ f32x4 mfma16(half8 a, half8 b, f32x4 c) {
  return __builtin_amdgcn_mfma_f32_16x16x32_f16(a, b, c, 0, 0, 0);
}
__device__ __forceinline__ half8 ldfrag(const _Float16* p) { return *(const half8*)p; }
__device__ __forceinline__ half8 zfrag() { half8 z = {}; return z; }

// ---------------- x -> fp16 ----------------
__global__ __launch_bounds__(256) void cvt_x(const float* __restrict__ x,
                                             _Float16* __restrict__ xh) {
  int i = blockIdx.x * 256 + threadIdx.x;  // 1048576 threads, 4 floats each
  float4 v = ((const float4*)x)[i];
  half4v h = { (_Float16)v.x, (_Float16)v.y, (_Float16)v.z, (_Float16)v.w };
  *(half4v*)(xh + i * 4) = h;
}

// ---------------- weight repack into MFMA fragment layouts ----------------
// Fragment = 64 lanes x 8 halves (512 halves). A-frag: A[m=l15][k=q8+j].
// B-frag: B[k=q8+j][n=l15]. Flat layout (halves):
//   AQ   [mb4][kb2]          @ 0       (q^T proj: A[m=out_ch][k=d]=Q_P[k][m])
//   AK   [t9][mb4][kb2]      @ 4096
//   BV   [t9][kb2][nb4]      @ 40960
//   B1   [kb2][nb4]          @ 77824
//   BF2  [t9][kb2][nb8]      @ 81920
//   BF3  [t9][kb4][nb4]      @ 155648   total 229376 halves
__global__ __launch_bounds__(256) void repack(
    const float* __restrict__ Kp, const float* __restrict__ Vp,
    const float* __restrict__ Qp, const float* __restrict__ W1,
    const float* __restrict__ F2, const float* __restrict__ F3,
    _Float16* __restrict__ out) {
  int e = blockIdx.x * 256 + threadIdx.x;  // 229376 total
  int j = e & 7, l = (e >> 3) & 63, f = e >> 9;
  int l15 = l & 15, q8 = (l >> 4) * 8;
  float v;
  if (f < 8)        { int mb = f >> 1, kb = f & 1;
                      v = Qp[(kb*32 + q8 + j) * 64 + mb*16 + l15]; }
  else if (f < 80)  { int g = f - 8, t = g >> 3, mb = (g >> 1) & 3, kb = g & 1;
                      v = Kp[(kb*32 + q8 + j) * 576 + t*64 + mb*16 + l15]; }
  else if (f < 152) { int g = f - 80, t = g >> 3, kb = (g >> 2) & 1, nb = g & 3;
                      v = Vp[(kb*32 + q8 + j) * 576 + t*64 + nb*16 + l15]; }
  else if (f < 160) { int g = f - 152, kb = g >> 2, nb = g & 3;
                      v = W1[(kb*32 + q8 + j) * 64 + nb*16 + l15]; }
  else if (f < 304) { int g = f - 160, t = g >> 4, kb = (g >> 3) & 1, nb = g & 7;
                      v = F2[(t*64 + kb*32 + q8 + j) * 128 + nb*16 + l15]; }
  else              { int g = f - 304, t = g >> 4, kb = (g >> 2) & 3, nb = g & 3;
                      v = F3[(t*128 + kb*32 + q8 + j) * 64 + nb*16 + l15]; }
  out[e] = (_Float16)v;
}

// ---------------- attention + ff1, 1 wave = 16 pixels ----------------
// q,k computed transposed (ch x pix, C-layout) so the tap score is a per-lane
// 32-FMA partial + 2-step quad butterfly; lane <-> pixel (l15) alignment means
// softmax alphas need no cross-lane broadcast for the (alpha*x)@V combine.
__global__ __launch_bounds__(256) void attn_ff1(
    const _Float16* __restrict__ xh, const _Float16* __restrict__ wf,
    const float* __restrict__ f1b, _Float16* __restrict__ t1g) {
  const int lane = threadIdx.x & 63, wid = threadIdx.x >> 6;
  const int l15 = lane & 15, q8 = (lane >> 4) * 8;
  const int pb = blockIdx.x * 4 + wid;
  const int p0 = pb * 16;
  const int h = (p0 >> 7) & 127, w0 = p0 & 127;
  const int myw = w0 + l15;
  const int mypix = p0 + l15;

  const _Float16* AQ = wf;
  const _Float16* AK = wf + 4096;
  const _Float16* BV = wf + 40960;
  const _Float16* B1 = wf + 77824;

  __shared__ _Float16 lds[4][16 * 72];  // per-wave 16x64 tile, padded rows

  // own-x fragments: serve as B (x^T) for q/k proj and A for v proj
  const _Float16* xp = xh + mypix * 64 + q8;
  half8 ax0 = ldfrag(xp), ax1 = ldfrag(xp + 32);

  // q^T tiles per 16-ch block (cb): D[m=ch][n=pix]
  f32x4 qT[4];
#pragma unroll
  for (int cb = 0; cb < 4; ++cb) {
    f32x4 c = {};
    c = mfma16(ldfrag(AQ + (cb*2 + 0) * 512 + lane * 8), ax0, c);
    c = mfma16(ldfrag(AQ + (cb*2 + 1) * 512 + lane * 8), ax1, c);
    qT[cb] = c;
  }

  // pass 1: scores (masked-then-/3 semantics: OOB tap -> score exactly 0)
  float sc0[9], sc1[9];
#pragma unroll
  for (int t = 0; t < 9; ++t) {
    const int dh = t / 3 - 1, dw = t % 3 - 1;
    sc0[t] = 0.f; sc1[t] = 0.f;
    if ((unsigned)(h + dh) >= 128u) continue;          // wave-uniform
    const bool cv = (unsigned)(myw + dw) < 128u;       // per-pixel col check
    const _Float16* sp = xh + (mypix + dh * 128 + dw) * 64 + q8;
    half8 sx0 = cv ? ldfrag(sp) : zfrag();
    half8 sx1 = cv ? ldfrag(sp + 32) : zfrag();
    float pa = 0.f, pbh = 0.f;
#pragma unroll
    for (int cb = 0; cb < 4; ++cb) {
      f32x4 c = {};
      c = mfma16(ldfrag(AK + ((t*4 + cb)*2 + 0) * 512 + lane * 8), sx0, c);
      c = mfma16(ldfrag(AK + ((t*4 + cb)*2 + 1) * 512 + lane * 8), sx1, c);
      float d = qT[cb].x * c.x + qT[cb].y * c.y + qT[cb].z * c.z + qT[cb].w * c.w;
      if (cb < 2) pa += d; else pbh += d;
    }
    pa  += __shfl_xor(pa, 16, 64);  pa  += __shfl_xor(pa, 32, 64);
    pbh += __shfl_xor(pbh, 16, 64); pbh += __shfl_xor(pbh, 32, 64);
    sc0[t] = pa * (1.f / 3.f); sc1[t] = pbh * (1.f / 3.f);
  }

  // softmax over taps, per lane (lane's pixel = l15); both heads
  float a0[9], a1[9];
  {
    float m0 = sc0[0], m1 = sc1[0];
#pragma unroll
    for (int t = 1; t < 9; ++t) { m0 = fmaxf(m0, sc0[t]); m1 = fmaxf(m1, sc1[t]); }
    float s0 = 0.f, s1 = 0.f;
#pragma unroll
    for (int t = 0; t < 9; ++t) {
      a0[t] = __expf(sc0[t] - m0); s0 += a0[t];
      a1[t] = __expf(sc1[t] - m1); s1 += a1[t];
    }
    s0 = 1.f / s0; s1 = 1.f / s1;
#pragma unroll
    for (int t = 0; t < 9; ++t) { a0[t] *= s0; a1[t] *= s1; }
  }

  // pass 2: attn = sum_t (alpha_t(p,head) * x(p+off_t)) @ V_chunk_t[head cols]
  f32x4 at[4] = {};
#pragma unroll
  for (int t = 0; t < 9; ++t) {
    const int dh = t / 3 - 1, dw = t % 3 - 1;
    if ((unsigned)(h + dh) >= 128u) continue;
    const bool cv = (unsigned)(myw + dw) < 128u;
    const _Float16* sp = xh + (mypix + dh * 128 + dw) * 64 + q8;
    half8 sx0 = cv ? ldfrag(sp) : zfrag();
    half8 sx1 = cv ? ldfrag(sp + 32) : zfrag();
    _Float16 h0 = (_Float16)a0[t], h1 = (_Float16)a1[t];
    half8 b0 = {h0, h0, h0, h0, h0, h0, h0, h0};
    half8 b1 = {h1, h1, h1, h1, h1, h1, h1, h1};
    half8 s00 = sx0 * b0, s01 = sx1 * b0;
    half8 s10 = sx0 * b1, s11 = sx1 * b1;
#pragma unroll
    for (int nb = 0; nb < 2; ++nb) {
      at[nb]     = mfma16(s00, ldfrag(BV + ((t*2 + 0)*4 + nb)     * 512 + lane * 8), at[nb]);
      at[nb]     = mfma16(s01, ldfrag(BV + ((t*2 + 1)*4 + nb)     * 512 + lane * 8), at[nb]);
      at[nb + 2] = mfma16(s10, ldfrag(BV + ((t*2 + 0)*4 + nb + 2) * 512 + lane * 8), at[nb + 2]);
      at[nb + 2] = mfma16(s11, ldfrag(BV + ((t*2 + 1)*4 + nb + 2) * 512 + lane * 8), at[nb + 2]);
    }
  }

  // C-layout -> LDS [pixel][ch] (fp16) for ff1 A-fragments
  _Float16* myt = lds[wid];
#pragma unroll
  for (int nb = 0; nb < 4; ++nb)
#pragma unroll
    for (int r = 0; r < 4; ++r)
      myt[((lane >> 4) * 4 + r) * 72 + nb * 16 + l15] = (_Float16)at[nb][r];
  __syncthreads();

  half8 aa0 = ldfrag(myt + l15 * 72 + q8);
  half8 aa1 = ldfrag(myt + l15 * 72 + 32 + q8);
  f32x4 t1a[4];
#pragma unroll
  for (int nb = 0; nb < 4; ++nb) {
    f32x4 c = {};
    c = mfma16(aa0, ldfrag(B1 + (0 * 4 + nb) * 512 + lane * 8), c);
    c = mfma16(aa1, ldfrag(B1 + (1 * 4 + nb) * 512 + lane * 8), c);
    t1a[nb] = c;
  }
#pragma unroll
  for (int nb = 0; nb < 4; ++nb) {
    float bv = f1b[nb * 16 + l15];
#pragma unroll
    for (int r = 0; r < 4; ++r) {
      float v = fmaxf(t1a[nb][r] + bv, 0.f);
      t1g[(p0 + (lane >> 4) * 4 + r) * 64 + nb * 16 + l15] = (_Float16)v;
    }
  }
}

// ---------------- 3x3 conv + bias + relu as 9 shifted GEMMs ---------------
// 1 wave = 32 pixels (2 M-blocks) so each B-fragment feeds 2 MFMAs.
template <int KB, int NB>
__global__ __launch_bounds__(256) void conv3x3(
    const _Float16* __restrict__ in, const _Float16* __restrict__ wfrag,
    const float* __restrict__ bias, void* __restrict__ outp, int out_fp32) {
  const int lane = threadIdx.x & 63;
  const int l15 = lane & 15, q8 = (lane >> 4) * 8;
  const int pb = blockIdx.x * 4 + (threadIdx.x >> 6);
  const int p0 = pb * 32;
  const int h = (p0 >> 7) & 127, w0 = p0 & 127;
  const int CIN = KB * 32, COUT = NB * 16;

  f32x4 acc[2][NB];
#pragma unroll
  for (int m = 0; m < 2; ++m)
#pragma unroll
    for (int nb = 0; nb < NB; ++nb) acc[m][nb] = f32x4{};

#pragma unroll
  for (int t = 0; t < 9; ++t) {
    const int dh = t / 3 - 1, dw = t % 3 - 1;
    if ((unsigned)(h + dh) >= 128u) continue;  // zero-pad row, wave-uniform
    half8 a[2][KB];
#pragma unroll
    for (int m = 0; m < 2; ++m) {
      const bool cv = (unsigned)(w0 + m * 16 + l15 + dw) < 128u;
      const _Float16* sp = in + (p0 + m * 16 + l15 + dh * 128 + dw) * CIN + q8;
#pragma unroll
      for (int kb = 0; kb < KB; ++kb) a[m][kb] = cv ? ldfrag(sp + kb * 32) : zfrag();
    }
#pragma unroll
    for (int nb = 0; nb < NB; ++nb) {
      f32x4 c0 = acc[0][nb], c1 = acc[1][nb];
#pragma unroll
      for (int kb = 0; kb < KB; ++kb) {
        half8 b = ldfrag(wfrag + ((t * KB + kb) * NB + nb) * 512 + lane * 8);
        c0 = mfma16(a[0][kb], b, c0);
        c1 = mfma16(a[1][kb], b, c1);
      }
      acc[0][nb] = c0; acc[1][nb] = c1;
    }
  }

#pragma unroll
  for (int m = 0; m < 2; ++m)
#pragma unroll
    for (int nb = 0; nb < NB; ++nb) {
      float bv = bias[nb * 16 + l15];
#pragma unroll
      for (int r = 0; r < 4; ++r) {
        float v = fmaxf(acc[m][nb][r] + bv, 0.f);
        int idx = (p0 + m * 16 + (lane >> 4) * 4 + r) * COUT + nb * 16 + l15;
        if (out_fp32) ((float*)outp)[idx] = v;
        else          ((_Float16*)outp)[idx] = (_Float16)v;
      }
    }
}

extern "C" void kernel_launch(void* const* d_in, const int* in_sizes, int n_in,
                              void* d_out, int out_size, void* d_ws, size_t ws_size,
                              hipStream_t stream) {
  (void)in_sizes; (void)n_in; (void)out_size; (void)ws_size;
  const float* x   = (const float*)d_in[0];
  const float* Kp  = (const float*)d_in[1];
  const float* Vp  = (const float*)d_in[2];
  const float* Qp  = (const float*)d_in[3];
  const float* f1w = (const float*)d_in[4];
  const float* f1b = (const float*)d_in[5];
  const float* f2w = (const float*)d_in[6];
  const float* f2b = (const float*)d_in[7];
  const float* f3w = (const float*)d_in[8];
  const float* f3b = (const float*)d_in[9];

  // ws: xh (4194304 halves) | weight frags (229376 halves) | t2 (8388608 halves)
  //  = 25.6 MB total. t1 (fp16, 8.4 MB) lives in d_out (16.8 MB), overwritten
  //  by conv3's final fp32 output.
  _Float16* xh  = (_Float16*)d_ws;
  _Float16* wf  = xh + 4194304;
  _Float16* t2g = wf + 229376;
  _Float16* t1g = (_Float16*)d_out;

  cvt_x<<<4096, 256, 0, stream>>>(x, xh);
  repack<<<896, 256, 0, stream>>>(Kp, Vp, Qp, f1w, f2w, f3w, wf);
  attn_ff1<<<1024, 256, 0, stream>>>(xh, wf, f1b, t1g);
  conv3x3<2, 8><<<512, 256, 0, stream>>>(t1g, wf + 81920, f2b, t2g, 0);
  conv3x3<4, 4><<<512, 256, 0, stream>>>(t2g, wf + 155648, f3b, d_out, 1);
}

// Round 3
// 162.394 us; speedup vs baseline: 9.7057x; 1.2436x over previous
//
#include <hip/hip_runtime.h>

// B=4, H=W=128, D=64, NH=2, hd=32, 9 taps. All inputs fp32; compute in fp16 MFMA.
// Input order: x, K_P[64,576], V_P[64,576], Q_P[64,64], ff1_k[64,64], ff1_b[64],
//              ff2_k[3,3,64,128], ff2_b[128], ff3_k[3,3,128,64], ff3_b[64]
//
// Structure: block = 4 waves = 1 image row (128 px); wave = 32 px (2 M-tiles).
// Per-tap weight fragments staged to LDS once per block via global_load_lds
// (width 16), double-buffered across the tap loop.

typedef _Float16 half8 __attribute__((ext_vector_type(8)));
typedef _Float16 half4v __attribute__((ext_vector_type(4)));
typedef float f32x4 __attribute__((ext_vector_type(4)));

__device__ __forceinline__ f32x4 mfma16(half8 a, half8 b, f32x4 c) {
  return __builtin_amdgcn_mfma_f32_16x16x32_f16(a, b, c, 0, 0, 0);
}
__device__ __forceinline__ half8 ldfrag(const _Float16* p) { return *(const half8*)p; }
__device__ __forceinline__ half8 zfrag() { half8 z = {}; return z; }

// async global->LDS: per-lane global addr, WAVE-UNIFORM lds base; lane i lands
// at ldsbase + i*16 B (matches [lane][8-half] fragment layout exactly).
__device__ __forceinline__ void gload_lds16(const _Float16* g, _Float16* l) {
  __builtin_amdgcn_global_load_lds(
      (const __attribute__((address_space(1))) void*)g,
      (__attribute__((address_space(3))) void*)l, 16, 0, 0);
}
// stage nfrag fragments (512 halves each), split across the block's 4 waves
__device__ __forceinline__ void stage_frags(const _Float16* g, _Float16* l,
                                            int nfrag, int wid, int lane) {
#pragma unroll
  for (int c0 = 0; c0 < 4; ++c0) {
    int c = wid + c0 * 4;
    if (c < nfrag) gload_lds16(g + c * 512 + lane * 8, l + c * 512);
  }
}

// ---------------- x -> fp16 ----------------
__global__ __launch_bounds__(256) void cvt_x(const float* __restrict__ x,
                                             _Float16* __restrict__ xh) {
  int i = blockIdx.x * 256 + threadIdx.x;  // 1048576 threads, 4 floats each
  float4 v = ((const float4*)x)[i];
  half4v h = { (_Float16)v.x, (_Float16)v.y, (_Float16)v.z, (_Float16)v.w };
  *(half4v*)(xh + i * 4) = h;
}

// ---------------- weight repack into MFMA fragment layouts ----------------
// Fragment = 64 lanes x 8 halves (512 halves). A-frag: A[m=l15][k=q8+j].
// B-frag: B[k=q8+j][n=l15]. Flat layout (halves):
//   AQ  [mb4][kb2]      @ 0       AK  [t9][cb4][kb2]  @ 4096
//   BV  [t9][kb2][nb4]  @ 40960   B1  [kb2][nb4]      @ 77824
//   BF2 [t9][kb2][nb8]  @ 81920   BF3 [t9][kb4][nb4]  @ 155648  (229376 total)
__global__ __launch_bounds__(256) void repack(
    const float* __restrict__ Kp, const float* __restrict__ Vp,
    const float* __restrict__ Qp, const float* __restrict__ W1,
    const float* __restrict__ F2, const float* __restrict__ F3,
    _Float16* __restrict__ out) {
  int e = blockIdx.x * 256 + threadIdx.x;  // 229376 total
  int j = e & 7, l = (e >> 3) & 63, f = e >> 9;
  int l15 = l & 15, q8 = (l >> 4) * 8;
  float v;
  if (f < 8)        { int mb = f >> 1, kb = f & 1;
                      v = Qp[(kb*32 + q8 + j) * 64 + mb*16 + l15]; }
  else if (f < 80)  { int g = f - 8, t = g >> 3, mb = (g >> 1) & 3, kb = g & 1;
                      v = Kp[(kb*32 + q8 + j) * 576 + t*64 + mb*16 + l15]; }
  else if (f < 152) { int g = f - 80, t = g >> 3, kb = (g >> 2) & 1, nb = g & 3;
                      v = Vp[(kb*32 + q8 + j) * 576 + t*64 + nb*16 + l15]; }
  else if (f < 160) { int g = f - 152, kb = g >> 2, nb = g & 3;
                      v = W1[(kb*32 + q8 + j) * 64 + nb*16 + l15]; }
  else if (f < 304) { int g = f - 160, t = g >> 4, kb = (g >> 3) & 1, nb = g & 7;
                      v = F2[(t*64 + kb*32 + q8 + j) * 128 + nb*16 + l15]; }
  else              { int g = f - 304, t = g >> 4, kb = (g >> 2) & 3, nb = g & 3;
                      v = F3[(t*128 + kb*32 + q8 + j) * 64 + nb*16 + l15]; }
  out[e] = (_Float16)v;
}

// ---------------- attention + ff1 ----------------
// Wave = 32 px (2 M-tiles). q,k computed transposed (ch x pix, C-layout) so the
// tap score is a per-lane 4-FMA dot + 2-step shfl butterfly; lane<->pixel (l15)
// alignment means alphas need no cross-lane broadcast for (alpha*x)@V.
__global__ __launch_bounds__(256) void attn_ff1(
    const _Float16* __restrict__ xh, const _Float16* __restrict__ wf,
    const float* __restrict__ f1b, _Float16* __restrict__ t1g) {
  const int lane = threadIdx.x & 63, wid = threadIdx.x >> 6;
  const int l15 = lane & 15, q8 = (lane >> 4) * 8;
  const int row = blockIdx.x;              // 512 rows (block = one image row)
  const int p0 = row * 128 + wid * 32;     // wave's 32 pixels
  const int h = row & 127;
  const int w0 = wid * 32;

  const _Float16* AQ = wf;
  const _Float16* AK = wf + 4096;
  const _Float16* BV = wf + 40960;
  const _Float16* B1 = wf + 77824;

  // union: 2x4096-half tap dbuf | 4x2304-half ff1 transpose tiles
  __shared__ _Float16 smem[9216];

  // own-x fragments per M-tile
  half8 ax0[2], ax1[2];
#pragma unroll
  for (int m = 0; m < 2; ++m) {
    const _Float16* xp = xh + (p0 + m * 16 + l15) * 64 + q8;
    ax0[m] = ldfrag(xp); ax1[m] = ldfrag(xp + 32);
  }

  // q^T tiles: D[m=ch][n=pix]
  f32x4 qT[2][4];
#pragma unroll
  for (int cb = 0; cb < 4; ++cb) {
    half8 aq0 = ldfrag(AQ + (cb * 2 + 0) * 512 + lane * 8);
    half8 aq1 = ldfrag(AQ + (cb * 2 + 1) * 512 + lane * 8);
#pragma unroll
    for (int m = 0; m < 2; ++m) {
      f32x4 c = {};
      c = mfma16(aq0, ax0[m], c);
      c = mfma16(aq1, ax1[m], c);
      qT[m][cb] = c;
    }
  }

  // -------- pass 1: scores (masked-then-/3: OOB tap -> score exactly 0) -----
  float sc[2][2][9];
#pragma unroll
  for (int m = 0; m < 2; ++m)
#pragma unroll
    for (int hd = 0; hd < 2; ++hd)
#pragma unroll
      for (int t = 0; t < 9; ++t) sc[m][hd][t] = 0.f;

  stage_frags(AK, smem, 8, wid, lane);
#pragma unroll
  for (int t = 0; t < 9; ++t) {
    _Float16* bw = smem + (t & 1) * 4096;
    __syncthreads();                       // tap-t staging complete (vmcnt drain)
    const int dh = t / 3 - 1, dw = t % 3 - 1;
    const bool rowok = (unsigned)(h + dh) < 128u;   // block-uniform
    half8 sx0[2], sx1[2];
    if (rowok) {                            // A-loads BEFORE stage-next
#pragma unroll
      for (int m = 0; m < 2; ++m) {
        const bool cv = (unsigned)(w0 + m * 16 + l15 + dw) < 128u;
        const _Float16* sp = xh + (p0 + m * 16 + l15 + dh * 128 + dw) * 64 + q8;
        sx0[m] = cv ? ldfrag(sp) : zfrag();
        sx1[m] = cv ? ldfrag(sp + 32) : zfrag();
      }
    }
    if (t < 8) stage_frags(AK + (t + 1) * 4096, smem + ((t + 1) & 1) * 4096, 8, wid, lane);
    if (!rowok) continue;
    half8 kf[8];
#pragma unroll
    for (int f = 0; f < 8; ++f) kf[f] = ldfrag(bw + f * 512 + lane * 8);
#pragma unroll
    for (int m = 0; m < 2; ++m) {
      float pa = 0.f, pb = 0.f;
#pragma unroll
      for (int cb = 0; cb < 4; ++cb) {
        f32x4 c = {};
        c = mfma16(kf[cb * 2 + 0], sx0[m], c);
        c = mfma16(kf[cb * 2 + 1], sx1[m], c);
        float d = qT[m][cb].x * c.x + qT[m][cb].y * c.y
                + qT[m][cb].z * c.z + qT[m][cb].w * c.w;
        if (cb < 2) pa += d; else pb += d;
      }
      pa += __shfl_xor(pa, 16, 64); pa += __shfl_xor(pa, 32, 64);
      pb += __shfl_xor(pb, 16, 64); pb += __shfl_xor(pb, 32, 64);
      sc[m][0][t] = pa * (1.f / 3.f);
      sc[m][1][t] = pb * (1.f / 3.f);
    }
  }

  // -------- softmax over taps (per lane = per pixel), alphas in place -------
#pragma unroll
  for (int m = 0; m < 2; ++m)
#pragma unroll
    for (int hd = 0; hd < 2; ++hd) {
      float mx = sc[m][hd][0];
#pragma unroll
      for (int t = 1; t < 9; ++t) mx = fmaxf(mx, sc[m][hd][t]);
      float s = 0.f;
#pragma unroll
      for (int t = 0; t < 9; ++t) { sc[m][hd][t] = __expf(sc[m][hd][t] - mx); s += sc[m][hd][t]; }
      s = 1.f / s;
#pragma unroll
      for (int t = 0; t < 9; ++t) sc[m][hd][t] *= s;
    }

  // -------- pass 2: attn = sum_t (alpha_t * x_shift) @ V_chunk_t ------------
  __syncthreads();                         // everyone done with pass-1 LDS
  stage_frags(BV, smem, 8, wid, lane);
  f32x4 at[2][4];
#pragma unroll
  for (int m = 0; m < 2; ++m)
#pragma unroll
    for (int nb = 0; nb < 4; ++nb) at[m][nb] = f32x4{};
#pragma unroll
  for (int t = 0; t < 9; ++t) {
    _Float16* bw = smem + (t & 1) * 4096;
    __syncthreads();
    const int dh = t / 3 - 1, dw = t % 3 - 1;
    const bool rowok = (unsigned)(h + dh) < 128u;
    half8 sx0[2], sx1[2];
    if (rowok) {
#pragma unroll
      for (int m = 0; m < 2; ++m) {
        const bool cv = (unsigned)(w0 + m * 16 + l15 + dw) < 128u;
        const _Float16* sp = xh + (p0 + m * 16 + l15 + dh * 128 + dw) * 64 + q8;
        sx0[m] = cv ? ldfrag(sp) : zfrag();
        sx1[m] = cv ? ldfrag(sp + 32) : zfrag();
      }
    }
    if (t < 8) stage_frags(BV + (t + 1) * 4096, smem + ((t + 1) & 1) * 4096, 8, wid, lane);
    if (!rowok) continue;
    half8 vf[8];
#pragma unroll
    for (int f = 0; f < 8; ++f) vf[f] = ldfrag(bw + f * 512 + lane * 8);
#pragma unroll
    for (int m = 0; m < 2; ++m) {
      _Float16 h0 = (_Float16)sc[m][0][t], h1 = (_Float16)sc[m][1][t];
      half8 b0 = {h0, h0, h0, h0, h0, h0, h0, h0};
      half8 b1 = {h1, h1, h1, h1, h1, h1, h1, h1};
      half8 s00 = sx0[m] * b0, s01 = sx1[m] * b0;
      half8 s10 = sx0[m] * b1, s11 = sx1[m] * b1;
#pragma unroll
      for (int nb = 0; nb < 2; ++nb) {
        at[m][nb]     = mfma16(s00, vf[0 * 4 + nb],     at[m][nb]);
        at[m][nb]     = mfma16(s01, vf[1 * 4 + nb],     at[m][nb]);
        at[m][nb + 2] = mfma16(s10, vf[0 * 4 + nb + 2], at[m][nb + 2]);
        at[m][nb + 2] = mfma16(s11, vf[1 * 4 + nb + 2], at[m][nb + 2]);
      }
    }
  }

  // -------- ff1 (C-layout -> LDS transpose -> A-frags) ----------------------
  __syncthreads();                         // done reading tap dbuf; repurpose
  _Float16* myt = smem + wid * 2304;       // wave-private 2x(16x72)
#pragma unroll
  for (int m = 0; m < 2; ++m)
#pragma unroll
    for (int nb = 0; nb < 4; ++nb)
#pragma unroll
      for (int r = 0; r < 4; ++r)
        myt[m * 1152 + ((lane >> 4) * 4 + r) * 72 + nb * 16 + l15] = (_Float16)at[m][nb][r];
  // same-wave write->read: compiler inserts lgkmcnt wait
#pragma unroll
  for (int m = 0; m < 2; ++m) {
    half8 aa0 = ldfrag(myt + m * 1152 + l15 * 72 + q8);
    half8 aa1 = ldfrag(myt + m * 1152 + l15 * 72 + 32 + q8);
#pragma unroll
    for (int nb = 0; nb < 4; ++nb) {
      f32x4 c = {};
      c = mfma16(aa0, ldfrag(B1 + (0 * 4 + nb) * 512 + lane * 8), c);
      c = mfma16(aa1, ldfrag(B1 + (1 * 4 + nb) * 512 + lane * 8), c);
      float bv = f1b[nb * 16 + l15];
#pragma unroll
      for (int r = 0; r < 4; ++r) {
        float v = fmaxf(c[r] + bv, 0.f);
        t1g[(p0 + m * 16 + (lane >> 4) * 4 + r) * 64 + nb * 16 + l15] = (_Float16)v;
      }
    }
  }
}

// ---------------- 3x3 conv + bias + relu as 9 shifted GEMMs ---------------
// Block = 1 row (128 px), wave = 32 px (2 M-tiles) x NB out-chan blocks.
// Per-tap 16 weight frags (16 KB) staged to LDS, double-buffered.
template <int KB, int NB>
__global__ __launch_bounds__(256) void conv3x3(
    const _Float16* __restrict__ in, const _Float16* __restrict__ wfrag,
    const float* __restrict__ bias, void* __restrict__ outp, int out_fp32) {
  const int lane = threadIdx.x & 63, wid = threadIdx.x >> 6;
  const int l15 = lane & 15, q8 = (lane >> 4) * 8;
  const int row = blockIdx.x;
  const int p0 = row * 128 + wid * 32;
  const int h = row & 127;
  const int w0 = wid * 32;
  const int CIN = KB * 32, COUT = NB * 16;

  __shared__ _Float16 smem[2 * 8192];      // 2 x 16-frag tap buffers

  f32x4 acc[2][NB];
#pragma unroll
  for (int m = 0; m < 2; ++m)
#pragma unroll
    for (int nb = 0; nb < NB; ++nb) acc[m][nb] = f32x4{};

  stage_frags(wfrag, smem, 16, wid, lane);
#pragma unroll
  for (int t = 0; t < 9; ++t) {
    _Float16* bw = smem + (t & 1) * 8192;
    __syncthreads();
    const int dh = t / 3 - 1, dw = t % 3 - 1;
    const bool rowok = (unsigned)(h + dh) < 128u;   // block-uniform
    half8 a[2][KB];
    if (rowok) {                            // A-loads BEFORE stage-next
#pragma unroll
      for (int m = 0; m < 2; ++m) {
        const bool cv = (unsigned)(w0 + m * 16 + l15 + dw) < 128u;
        const _Float16* sp = in + (p0 + m * 16 + l15 + dh * 128 + dw) * CIN + q8;
#pragma unroll
        for (int kb = 0; kb < KB; ++kb) a[m][kb] = cv ? ldfrag(sp + kb * 32) : zfrag();
      }
    }
    if (t < 8) stage_frags(wfrag + (t + 1) * 8192, smem + ((t + 1) & 1) * 8192, 16, wid, lane);
    if (!rowok) continue;
#pragma unroll
    for (int nb = 0; nb < NB; ++nb) {
#pragma unroll
      for (int kb = 0; kb < KB; ++kb) {
        half8 b = ldfrag(bw + (kb * NB + nb) * 512 + lane * 8);
        acc[0][nb] = mfma16(a[0][kb], b, acc[0][nb]);
        acc[1][nb] = mfma16(a[1][kb], b, acc[1][nb]);
      }
    }
  }

#pragma unroll
  for (int m = 0; m < 2; ++m)
#pragma unroll
    for (int nb = 0; nb < NB; ++nb) {
      float bv = bias[nb * 16 + l15];
#pragma unroll
      for (int r = 0; r < 4; ++r) {
        float v = fmaxf(acc[m][nb][r] + bv, 0.f);
        int idx = (p0 + m * 16 + (lane >> 4) * 4 + r) * COUT + nb * 16 + l15;
        if (out_fp32) ((float*)outp)[idx] = v;
        else          ((_Float16*)outp)[idx] = (_Float16)v;
      }
    }
}

extern "C" void kernel_launch(void* const* d_in, const int* in_sizes, int n_in,
                              void* d_out, int out_size, void* d_ws, size_t ws_size,
                              hipStream_t stream) {
  (void)in_sizes; (void)n_in; (void)out_size; (void)ws_size;
  const float* x   = (const float*)d_in[0];
  const float* Kp  = (const float*)d_in[1];
  const float* Vp  = (const float*)d_in[2];
  const float* Qp  = (const float*)d_in[3];
  const float* f1w = (const float*)d_in[4];
  const float* f1b = (const float*)d_in[5];
  const float* f2w = (const float*)d_in[6];
  const float* f2b = (const float*)d_in[7];
  const float* f3w = (const float*)d_in[8];
  const float* f3b = (const float*)d_in[9];

  // ws: xh (4194304 halves) | weight frags (229376) | t2 (8388608) = 25.6 MB.
  // t1 (fp16, 8.4 MB) lives in d_out, overwritten by conv3's fp32 output.
  _Float16* xh  = (_Float16*)d_ws;
  _Float16* wf  = xh + 4194304;
  _Float16* t2g = wf + 229376;
  _Float16* t1g = (_Float16*)d_out;

  cvt_x<<<4096, 256, 0, stream>>>(x, xh);
  repack<<<896, 256, 0, stream>>>(Kp, Vp, Qp, f1w, f2w, f3w, wf);
  attn_ff1<<<512, 256, 0, stream>>>(xh, wf, f1b, t1g);
  conv3x3<2, 8><<<512, 256, 0, stream>>>(t1g, wf + 81920, f2b, t2g, 0);
  conv3x3<4, 4><<<512, 256, 0, stream>>>(t2g, wf + 155648, f3b, d_out, 1);
}